// Round 6
// baseline (132.302 us; speedup 1.0000x reference)
//
#include <hip/hip_runtime.h>
#include <stdint.h>

// Reference: X[256,256,32,32] f32 * mask, mask[b] = concat(ones(51ch),
// bernoulli(fold_in(key(101010), idx[b]), p=0.1, (205,32,32))).
// Evidence ledger:
//   r1->r2: idx device buffer is int64-layout (detector A/B) -- harness casts
//           to the declared annotation dtype; host jax itself is x64-OFF.
//   r2: 32-bit ORIGINAL mode (split pairing (i,i+n), word select)   FAILED
//   r3: 64-bit partitionable (0,i), (b1<<32)|b2                     FAILED
//   r4: 64-bit original (i,i+n), (b1<<32)|b2                        FAILED
//   r5: 32-bit partitionable (0,i), word = b2                       FAILED
// This round: 32-bit partitionable, word = b1 ^ b2 -- per JAX prng.py:
//   bit_width in [8,16,32] -> return convert(bits1 ^ bits2)
//   elem i: (b1,b2) = threefry2x32(key, hi32(i)=0, lo32(i)=i)
//   keep iff ((b1^b2) >> 9) <= 838860   (== bitcast-uniform < 0.1f exactly)
// Geometry (floats): example stride 262144; fixed 51*1024=52224=13056 quads;
// mem 205*1024=209920 elems. Tasks/example = 65536 quads.

#define EX_STRIDE    262144
#define FIXED_Q      13056
#define TASKS        65536

__device__ __forceinline__ uint32_t rotl32(uint32_t x, int d) {
    return (x << d) | (x >> (32 - d));
}

// JAX threefry2x32: 20 rounds, key injection every 4 rounds.
// Verified against jax/_src/prng.py rolled_loop_step key/round schedule.
__device__ __forceinline__ void threefry2x32(uint32_t k0, uint32_t k1,
                                             uint32_t& x0, uint32_t& x1) {
    const uint32_t k2 = k0 ^ k1 ^ 0x1BD11BDAu;
    x0 += k0; x1 += k1;
#define TF_R(r) { x0 += x1; x1 = rotl32(x1, r); x1 ^= x0; }
    TF_R(13) TF_R(15) TF_R(26) TF_R(6)
    x0 += k1; x1 += k2 + 1u;
    TF_R(17) TF_R(29) TF_R(16) TF_R(24)
    x0 += k2; x1 += k0 + 2u;
    TF_R(13) TF_R(15) TF_R(26) TF_R(6)
    x0 += k0; x1 += k1 + 3u;
    TF_R(17) TF_R(29) TF_R(16) TF_R(24)
    x0 += k1; x1 += k2 + 4u;
    TF_R(13) TF_R(15) TF_R(26) TF_R(6)
    x0 += k2; x1 += k0 + 5u;
#undef TF_R
}

// Partitionable 32-bit draw for element i: counts (0, i); word = b1 ^ b2.
// keep iff (word >> 9) <= 838860  (exact integer form of u < 0.1f).
__device__ __forceinline__ float apply32(uint32_t k0, uint32_t k1,
                                         uint32_t i, float v) {
    uint32_t y0 = 0u, y1 = i;
    threefry2x32(k0, k1, y0, y1);
    return (((y0 ^ y1) >> 9) <= 838860u) ? v : 0.0f;
}

// idx layout normalization (validated: buffer is int64 LE).
__global__ __launch_bounds__(256)
void normalize_idx_kernel(const int* __restrict__ raw, int* __restrict__ norm) {
    __shared__ int s_int64;
    const int t = threadIdx.x;
    if (t == 0) s_int64 = 1;
    __syncthreads();
    const int v = raw[t];
    if ((t & 1) && v != 0) s_int64 = 0;   // benign race: all writers store 0
    __syncthreads();
    if (s_int64) {
        norm[t] = raw[2 * t];             // int64 LE low word
    } else {
        norm[t] = v;
    }
}

__global__ __launch_bounds__(256)
void tied_dropout_kernel(const float* __restrict__ X,
                         const int* __restrict__ idx,
                         float* __restrict__ out) {
    const int b = blockIdx.y;

    // fold_in(base_key=(0,101010), idx[b]) = threefry on counts (0, idx).
    __shared__ uint32_t sk0, sk1;
    if (threadIdx.x == 0) {
        uint32_t f0 = 0u, f1 = (uint32_t)idx[b];
        threefry2x32(0u, 101010u, f0, f1);
        sk0 = f0; sk1 = f1;
    }
    __syncthreads();
    const uint32_t k0 = sk0, k1 = sk1;

    const int t = blockIdx.x * blockDim.x + threadIdx.x;   // 0..65535

    const size_t ex_off = (size_t)b * EX_STRIDE;
    const float4* __restrict__ X4 = reinterpret_cast<const float4*>(X + ex_off);
    float4* __restrict__ O4 = reinterpret_cast<float4*>(out + ex_off);

    if (t < FIXED_Q) {
        O4[t] = X4[t];                    // always-on channels
    } else {
        const uint32_t e = (uint32_t)((t - FIXED_Q) << 2);  // mem elem base
        float4 v = X4[t];
        v.x = apply32(k0, k1, e + 0u, v.x);
        v.y = apply32(k0, k1, e + 1u, v.y);
        v.z = apply32(k0, k1, e + 2u, v.z);
        v.w = apply32(k0, k1, e + 3u, v.w);
        O4[t] = v;
    }
}

extern "C" void kernel_launch(void* const* d_in, const int* in_sizes, int n_in,
                              void* d_out, int out_size, void* d_ws, size_t ws_size,
                              hipStream_t stream) {
    const float* X = (const float*)d_in[0];
    const int* idx_raw = (const int*)d_in[1];
    // d_in[2] = epoch (ignored; reference applies mask unconditionally)
    float* out = (float*)d_out;

    dim3 block(256, 1, 1);
    dim3 grid(TASKS / 256, 256, 1);       // (256, B=256)

    if (ws_size >= 256 * sizeof(int)) {
        int* idx_norm = (int*)d_ws;
        normalize_idx_kernel<<<1, 256, 0, stream>>>(idx_raw, idx_norm);
        tied_dropout_kernel<<<grid, block, 0, stream>>>(X, idx_norm, out);
    } else {
        tied_dropout_kernel<<<grid, block, 0, stream>>>(X, idx_raw, out);
    }
}

// Round 8
// 119.132 us; speedup vs baseline: 1.1106x; 1.1106x over previous
//
#include <hip/hip_runtime.h>
#include <stdint.h>

// Reference: X[256,256,32,32] f32 * mask, mask[b] = concat(ones(51ch),
// bernoulli(fold_in(key(101010), idx[b]), p=0.1, (205,32,32))).
// VERIFIED (r6 pass, absmax=0): 32-bit partitionable threefry draws,
//   elem i: (b1,b2) = threefry2x32(key, 0, i); word = b1 ^ b2;
//   keep iff (word >> 9) <= 838860  (== uniform < 0.1f exactly)
//   key = threefry2x32((0,101010),(0,idx[b])); idx buffer int64 LE.
// Perf r6: 132.3 us for 537 MB = 4.06 TB/s (64% of achievable). Theory:
// low MLP -- 1 load + ~600cyc hash chain + 1 store per wave. Fix: 2 quads
// per thread (loads issued up front) + nontemporal access.
// r7 compile fix: nontemporal builtins reject HIP_vector_type; use clang
// ext_vector_type(4) float (same 16B layout, dwordx4 codegen).
// Geometry (floats): example stride 262144; fixed 13056 quads; total 65536
// quads/example; half-split HALF=32768 so quad2 = t+HALF is always mem-region.

#define EX_STRIDE    262144
#define FIXED_Q      13056
#define HALF_T       32768

typedef float f32x4 __attribute__((ext_vector_type(4)));

__device__ __forceinline__ uint32_t rotl32(uint32_t x, int d) {
    return (x << d) | (x >> (32 - d));
}

// JAX threefry2x32: 20 rounds, key injection every 4 rounds.
__device__ __forceinline__ void threefry2x32(uint32_t k0, uint32_t k1,
                                             uint32_t& x0, uint32_t& x1) {
    const uint32_t k2 = k0 ^ k1 ^ 0x1BD11BDAu;
    x0 += k0; x1 += k1;
#define TF_R(r) { x0 += x1; x1 = rotl32(x1, r); x1 ^= x0; }
    TF_R(13) TF_R(15) TF_R(26) TF_R(6)
    x0 += k1; x1 += k2 + 1u;
    TF_R(17) TF_R(29) TF_R(16) TF_R(24)
    x0 += k2; x1 += k0 + 2u;
    TF_R(13) TF_R(15) TF_R(26) TF_R(6)
    x0 += k0; x1 += k1 + 3u;
    TF_R(17) TF_R(29) TF_R(16) TF_R(24)
    x0 += k1; x1 += k2 + 4u;
    TF_R(13) TF_R(15) TF_R(26) TF_R(6)
    x0 += k2; x1 += k0 + 5u;
#undef TF_R
}

// Verified draw: counts (0,i), word = b1^b2, keep iff (word>>9) <= 838860.
__device__ __forceinline__ float apply32(uint32_t k0, uint32_t k1,
                                         uint32_t i, float v) {
    uint32_t y0 = 0u, y1 = i;
    threefry2x32(k0, k1, y0, y1);
    return (((y0 ^ y1) >> 9) <= 838860u) ? v : 0.0f;
}

__device__ __forceinline__ void mask_quad(f32x4& v, uint32_t k0, uint32_t k1,
                                          uint32_t e) {
    v.x = apply32(k0, k1, e + 0u, v.x);
    v.y = apply32(k0, k1, e + 1u, v.y);
    v.z = apply32(k0, k1, e + 2u, v.z);
    v.w = apply32(k0, k1, e + 3u, v.w);
}

// idx layout normalization (validated: buffer is int64 LE).
__global__ __launch_bounds__(256)
void normalize_idx_kernel(const int* __restrict__ raw, int* __restrict__ norm) {
    __shared__ int s_int64;
    const int t = threadIdx.x;
    if (t == 0) s_int64 = 1;
    __syncthreads();
    const int v = raw[t];
    if ((t & 1) && v != 0) s_int64 = 0;   // benign race: all writers store 0
    __syncthreads();
    if (s_int64) {
        norm[t] = raw[2 * t];             // int64 LE low word
    } else {
        norm[t] = v;
    }
}

__global__ __launch_bounds__(256)
void tied_dropout_kernel(const float* __restrict__ X,
                         const int* __restrict__ idx,
                         float* __restrict__ out) {
    const int b = blockIdx.y;

    // fold_in(base_key=(0,101010), idx[b]) once per block.
    __shared__ uint32_t sk0, sk1;
    if (threadIdx.x == 0) {
        uint32_t f0 = 0u, f1 = (uint32_t)idx[b];
        threefry2x32(0u, 101010u, f0, f1);
        sk0 = f0; sk1 = f1;
    }
    __syncthreads();
    const uint32_t k0 = sk0, k1 = sk1;

    const int t = blockIdx.x * blockDim.x + threadIdx.x;   // 0..32767

    const size_t ex_off = (size_t)b * EX_STRIDE;
    const f32x4* __restrict__ X4 = reinterpret_cast<const f32x4*>(X + ex_off);
    f32x4* __restrict__ O4 = reinterpret_cast<f32x4*>(out + ex_off);

    // Issue BOTH loads before any hash work (MLP), then hash, then store.
    f32x4 va = __builtin_nontemporal_load(X4 + t);
    f32x4 vb = __builtin_nontemporal_load(X4 + t + HALF_T);

    // Quad B (t + 32768) is always in the mem region (32768 > 13056).
    mask_quad(vb, k0, k1, (uint32_t)((t + HALF_T - FIXED_Q) << 2));

    // Quad A: fixed channels pass through; mem channels masked.
    if (t >= FIXED_Q) {
        mask_quad(va, k0, k1, (uint32_t)((t - FIXED_Q) << 2));
    }

    __builtin_nontemporal_store(va, O4 + t);
    __builtin_nontemporal_store(vb, O4 + t + HALF_T);
}

extern "C" void kernel_launch(void* const* d_in, const int* in_sizes, int n_in,
                              void* d_out, int out_size, void* d_ws, size_t ws_size,
                              hipStream_t stream) {
    const float* X = (const float*)d_in[0];
    const int* idx_raw = (const int*)d_in[1];
    // d_in[2] = epoch (ignored; reference applies mask unconditionally)
    float* out = (float*)d_out;

    dim3 block(256, 1, 1);
    dim3 grid(HALF_T / 256, 256, 1);      // (128, B=256)

    if (ws_size >= 256 * sizeof(int)) {
        int* idx_norm = (int*)d_ws;
        normalize_idx_kernel<<<1, 256, 0, stream>>>(idx_raw, idx_norm);
        tied_dropout_kernel<<<grid, block, 0, stream>>>(X, idx_norm, out);
    } else {
        tied_dropout_kernel<<<grid, block, 0, stream>>>(X, idx_raw, out);
    }
}

// Round 10
// 116.851 us; speedup vs baseline: 1.1322x; 1.0195x over previous
//
#include <hip/hip_runtime.h>
#include <stdint.h>

// Reference: X[256,256,32,32] f32 * mask, mask[b] = concat(ones(51ch),
// bernoulli(fold_in(key(101010), idx[b]), p=0.1, (205,32,32))).
// VERIFIED PRNG (r6/r8 pass, absmax=0): 32-bit partitionable threefry,
//   elem i: (b1,b2) = threefry2x32(key, 0, i); word = b1 ^ b2;
//   keep iff (word >> 9) <= 838860  (== uniform < 0.1f exactly)
//   key = threefry2x32((0,101010),(0,idx[b]))
// idx layout: detector (validated r1->r2 A/B, passed r6/r8) — int64 LE
// => low word at raw[2b]; int32 => raw[b]. r9 swapped this for a direct
// long-long read and FAILED (absmax 5.125) -> NEVER bypass the detector.
// Perf ladder: r6 132.3us (1 quad) -> r8 119.1us (2 quads + nt, pre-kernel).
// r10: detector INLINED into main kernel (drops the serialized 1-block
// pre-launch; every block rescans the 1KB idx buffer from L2), 4 quads per
// thread with all loads issued before the hash burst, nt loads/stores.
// Geometry (floats): example stride 262144 = 65536 quads; fixed 13056 quads;
// quads at t, t+16384, t+32768, t+49152; 13056 < 16384 so quads 1-3 always
// mem-region; 13056 = 204*64 keeps the quad-0 branch wave-uniform.

#define EX_STRIDE    262144
#define FIXED_Q      13056
#define QUART_T      16384

typedef float f32x4 __attribute__((ext_vector_type(4)));

__device__ __forceinline__ uint32_t rotl32(uint32_t x, int d) {
    return (x << d) | (x >> (32 - d));
}

// JAX threefry2x32: 20 rounds, key injection every 4 rounds.
__device__ __forceinline__ void threefry2x32(uint32_t k0, uint32_t k1,
                                             uint32_t& x0, uint32_t& x1) {
    const uint32_t k2 = k0 ^ k1 ^ 0x1BD11BDAu;
    x0 += k0; x1 += k1;
#define TF_R(r) { x0 += x1; x1 = rotl32(x1, r); x1 ^= x0; }
    TF_R(13) TF_R(15) TF_R(26) TF_R(6)
    x0 += k1; x1 += k2 + 1u;
    TF_R(17) TF_R(29) TF_R(16) TF_R(24)
    x0 += k2; x1 += k0 + 2u;
    TF_R(13) TF_R(15) TF_R(26) TF_R(6)
    x0 += k0; x1 += k1 + 3u;
    TF_R(17) TF_R(29) TF_R(16) TF_R(24)
    x0 += k1; x1 += k2 + 4u;
    TF_R(13) TF_R(15) TF_R(26) TF_R(6)
    x0 += k2; x1 += k0 + 5u;
#undef TF_R
}

// Verified draw (byte-identical to r6/r8): counts (0,i), word = b1^b2,
// keep iff (word>>9) <= 838860.
__device__ __forceinline__ float apply32(uint32_t k0, uint32_t k1,
                                         uint32_t i, float v) {
    uint32_t y0 = 0u, y1 = i;
    threefry2x32(k0, k1, y0, y1);
    return (((y0 ^ y1) >> 9) <= 838860u) ? v : 0.0f;
}

__device__ __forceinline__ void mask_quad(f32x4& v, uint32_t k0, uint32_t k1,
                                          uint32_t e) {
    v.x = apply32(k0, k1, e + 0u, v.x);
    v.y = apply32(k0, k1, e + 1u, v.y);
    v.z = apply32(k0, k1, e + 2u, v.z);
    v.w = apply32(k0, k1, e + 3u, v.w);
}

__global__ __launch_bounds__(256)
void tied_dropout_kernel(const float* __restrict__ X,
                         const int* __restrict__ idx_raw,
                         float* __restrict__ out) {
    const int b = blockIdx.y;
    const int tid = threadIdx.x;

    // --- inlined idx-layout detection (validated logic from r6/r8) ---
    // int64 layout: all odd 32-bit words are 0 (values < 60000);
    // int32 layout: odd words uniform in [0,60000), all-zero impossible.
    __shared__ int s_i64;
    __shared__ uint32_t sk0, sk1;
    if (tid == 0) s_i64 = 1;
    __syncthreads();
    {
        const int v = idx_raw[tid];           // words 0..255 valid either way
        if ((tid & 1) && v != 0) s_i64 = 0;   // benign race: all writers store 0
    }
    __syncthreads();
    // --- fold_in(base_key=(0,101010), idx[b]), thread 0 + shared (as r8) ---
    if (tid == 0) {
        uint32_t f0 = 0u;
        uint32_t f1 = (uint32_t)(s_i64 ? idx_raw[2 * b] : idx_raw[b]);
        threefry2x32(0u, 101010u, f0, f1);
        sk0 = f0; sk1 = f1;
    }
    __syncthreads();
    const uint32_t k0 = sk0, k1 = sk1;

    const int t = blockIdx.x * blockDim.x + tid;   // 0..16383

    const size_t ex_off = (size_t)b * EX_STRIDE;
    const f32x4* __restrict__ X4 = reinterpret_cast<const f32x4*>(X + ex_off);
    f32x4* __restrict__ O4 = reinterpret_cast<f32x4*>(out + ex_off);

    // Issue ALL FOUR loads before any hash work (MLP), then hash, then store.
    f32x4 v0 = __builtin_nontemporal_load(X4 + t);
    f32x4 v1 = __builtin_nontemporal_load(X4 + t + QUART_T);
    f32x4 v2 = __builtin_nontemporal_load(X4 + t + 2 * QUART_T);
    f32x4 v3 = __builtin_nontemporal_load(X4 + t + 3 * QUART_T);

    // Quads 1-3 are always in the mem region (16384 > 13056).
    mask_quad(v1, k0, k1, (uint32_t)((t + 1 * QUART_T - FIXED_Q) << 2));
    mask_quad(v2, k0, k1, (uint32_t)((t + 2 * QUART_T - FIXED_Q) << 2));
    mask_quad(v3, k0, k1, (uint32_t)((t + 3 * QUART_T - FIXED_Q) << 2));

    // Quad 0: fixed channels pass through; mem channels masked (wave-uniform).
    if (t >= FIXED_Q) {
        mask_quad(v0, k0, k1, (uint32_t)((t - FIXED_Q) << 2));
    }

    __builtin_nontemporal_store(v0, O4 + t);
    __builtin_nontemporal_store(v1, O4 + t + QUART_T);
    __builtin_nontemporal_store(v2, O4 + t + 2 * QUART_T);
    __builtin_nontemporal_store(v3, O4 + t + 3 * QUART_T);
}

extern "C" void kernel_launch(void* const* d_in, const int* in_sizes, int n_in,
                              void* d_out, int out_size, void* d_ws, size_t ws_size,
                              hipStream_t stream) {
    const float* X = (const float*)d_in[0];
    const int* idx_raw = (const int*)d_in[1];
    // d_in[2] = epoch (ignored; reference applies mask unconditionally)
    float* out = (float*)d_out;

    dim3 block(256, 1, 1);
    dim3 grid(QUART_T / 256, 256, 1);     // (64, B=256)
    tied_dropout_kernel<<<grid, block, 0, stream>>>(X, idx_raw, out);
}